// Round 2
// baseline (322.607 us; speedup 1.0000x reference)
//
#include <hip/hip_runtime.h>
#include <math.h>

#define BATCH 16
#define LEN 480000
#define NDIM 9
#define CHUNK 1024
#define NCHUNK 469   /* ceil(480000/1024); last chunk = 768 elements */
#define AMP 0.1f

// native 4-float vector for nontemporal builtins (HIP float4 is a class type)
typedef float vfloat4 __attribute__((ext_vector_type(4)));

__device__ __forceinline__ float hw_fract(float x) {
#if __has_builtin(__builtin_amdgcn_fractf)
  return __builtin_amdgcn_fractf(x);
#else
  return x - floorf(x);
#endif
}
// sin(2*pi*x) for x in [0,1) — v_sin_f32 takes revolutions
__device__ __forceinline__ float hw_sin1(float x) {
#if __has_builtin(__builtin_amdgcn_sinf)
  return __builtin_amdgcn_sinf(x);
#else
  return __sinf(x * 6.283185307179586f);
#endif
}

// ---------------- Kernel A: per-1024-chunk f64 sums of f0 ----------------
__global__ __launch_bounds__(256) void sg_partial(const float* __restrict__ f0,
                                                  double* __restrict__ part) {
  const int c = blockIdx.x, b = blockIdx.y, t = threadIdx.x;
  const int i4 = c * 256 + t;
  float4 v = make_float4(0.f, 0.f, 0.f, 0.f);
  if (i4 < LEN / 4) v = ((const float4*)(f0 + (size_t)b * LEN))[i4];
  double s = (double)((v.x + v.y) + (v.z + v.w));
#pragma unroll
  for (int d = 32; d > 0; d >>= 1) s += __shfl_down(s, d, 64);
  __shared__ double ws[4];
  if ((t & 63) == 0) ws[t >> 6] = s;
  __syncthreads();
  if (t == 0) part[(size_t)b * NCHUNK + c] = (ws[0] + ws[1]) + (ws[2] + ws[3]);
}

// ---------------- Kernel B: main — base-sum + scan + sin + coalesced stores ----------------
__global__ __launch_bounds__(256) void sg_main(const float* __restrict__ f0,
                                               const float* __restrict__ rand_ini,
                                               const double* __restrict__ part,
                                               float* __restrict__ out) {
  const int c = blockIdx.x, b = blockIdx.y, t = threadIdx.x;
  const int lane = t & 63, w = t >> 6;

  __shared__ vfloat4 tile[2304];   // 1024 elements * 9 harmonics = 36 KB
  __shared__ float wsc[4];
  __shared__ double dred[4];
  __shared__ double cbs_s;

  // --- load this thread's 4 elements (coalesced float4) ---
  const int i4 = c * 256 + t;
  float4 v = make_float4(0.f, 0.f, 0.f, 0.f);
  if (i4 < LEN / 4) v = ((const float4*)(f0 + (size_t)b * LEN))[i4];
  const float fvv0 = v.x, fvv1 = v.y, fvv2 = v.z, fvv3 = v.w;
  const float gs = (v.x + v.y) + (v.z + v.w);

  // --- block-parallel f64 sum of preceding chunk sums: base = sum part[b][i], i<c ---
  const double* prow = part + (size_t)b * NCHUNK;
  double s = 0.0;
  if (t < c) s += prow[t];
  if (t + 256 < c) s += prow[t + 256];
#pragma unroll
  for (int d = 32; d > 0; d >>= 1) s += __shfl_down(s, d, 64);
  if (lane == 0) dred[w] = s;

  // --- wave-level inclusive scan of per-thread group sums ---
  float x = gs;
#pragma unroll
  for (int d = 1; d < 64; d <<= 1) {
    float y = __shfl_up(x, d, 64);
    if (lane >= d) x += y;
  }
  if (lane == 63) wsc[w] = x;
  __syncthreads();
  if (t == 0) cbs_s = (dred[0] + dred[1]) + (dred[2] + dred[3]);
  __syncthreads();

  const float t0 = wsc[0], t1 = wsc[1], t2 = wsc[2];
  const float wpre = (w > 0 ? t0 : 0.f) + (w > 1 ? t1 : 0.f) + (w > 2 ? t2 : 0.f);
  float P = wpre + (x - gs);            // exclusive in-chunk prefix for this thread

  // --- per-harmonic base phase: frac(rand + h/24000 * chunk_base), f64 once ---
  const double cb = cbs_s;
  float phi0[NDIM], hsf[NDIM];
#pragma unroll
  for (int h = 0; h < NDIM; ++h) {
    double hs = (double)(h + 1) * (1.0 / 24000.0);
    double p0 = (double)rand_ini[b * NDIM + h] + hs * cb;
    p0 -= floor(p0);
    phi0[h] = (float)p0;
    hsf[h] = (float)hs;
  }

  // --- sines for 4 elements x 9 harmonics ---
  float sv[4][NDIM];
  float uvv[4];
  const float fvv[4] = {fvv0, fvv1, fvv2, fvv3};
#pragma unroll
  for (int e = 0; e < 4; ++e) {
    const float f = fvv[e];
    P += f;                             // inclusive prefix (relative to chunk)
    uvv[e] = (f > 0.f) ? 1.f : 0.f;
    const float amp = AMP * uvv[e];
#pragma unroll
    for (int h = 0; h < NDIM; ++h)
      sv[e][h] = amp * hw_sin1(hw_fract(phi0[h] + hsf[h] * P));
  }

  // --- stage 36 floats -> LDS as 9 float4 (idx 9t+j: conflict-free in 8-lane phases) ---
#pragma unroll
  for (int j = 0; j < 9; ++j) {
    const int i0 = 4 * j;
    vfloat4 q;
    q.x = sv[(i0    ) / 9][(i0    ) % 9];
    q.y = sv[(i0 + 1) / 9][(i0 + 1) % 9];
    q.z = sv[(i0 + 2) / 9][(i0 + 2) % 9];
    q.w = sv[(i0 + 3) / 9][(i0 + 3) % 9];
    tile[t * 9 + j] = q;
  }
  __syncthreads();   // last barrier — no global stores issued yet

  // --- coalesced NONTEMPORAL stores: output is write-once, never re-read.
  //     Keeps 307 MB of streaming writes from evicting f0 out of per-XCD L2
  //     (f0 ~30.7 MB ~ aggregate L2; same grid shape => same block->XCD map
  //      as sg_partial, so the f0 re-read above can hit L2). ---
  vfloat4* out4 = (vfloat4*)out;
  const int base = c * CHUNK;
  const int valid = min(CHUNK, LEN - base);
  const int nf4 = (valid * NDIM) >> 2;
  const size_t gb4 = ((size_t)b * LEN * NDIM + (size_t)base * NDIM) >> 2;
#pragma unroll
  for (int k = 0; k < 9; ++k) {
    const int idx = k * 256 + t;
    if (idx < nf4) __builtin_nontemporal_store(tile[idx], &out4[gb4 + idx]);
  }
  const size_t uv4_base = ((size_t)BATCH * LEN * NDIM) / 4 + ((size_t)b * LEN) / 4;
  if (i4 < LEN / 4) {
    vfloat4 u;
    u.x = uvv[0]; u.y = uvv[1]; u.z = uvv[2]; u.w = uvv[3];
    __builtin_nontemporal_store(u, &out4[uv4_base + i4]);
  }
}

extern "C" void kernel_launch(void* const* d_in, const int* in_sizes, int n_in,
                              void* d_out, int out_size, void* d_ws, size_t ws_size,
                              hipStream_t stream) {
  const float* f0 = (const float*)d_in[0];
  const float* rand_ini = (const float*)d_in[1];
  float* out = (float*)d_out;

  double* part = (double*)d_ws;   // BATCH*NCHUNK f64 partial chunk sums

  dim3 grid(NCHUNK, BATCH);
  sg_partial<<<grid, 256, 0, stream>>>(f0, part);
  sg_main<<<grid, 256, 0, stream>>>(f0, rand_ini, part, out);
}

// Round 5
// 322.285 us; speedup vs baseline: 1.0010x; 1.0010x over previous
//
#include <hip/hip_runtime.h>
#include <math.h>

#define BATCH 16
#define LEN 480000
#define NDIM 9
#define CHUNK 1024
#define NCHUNK 469   /* ceil(480000/1024); last chunk = 768 elements */
#define AMP 0.1f

// native 4-float vector for nontemporal builtins (HIP float4 is a class type)
typedef float vfloat4 __attribute__((ext_vector_type(4)));

__device__ __forceinline__ float hw_fract(float x) {
#if __has_builtin(__builtin_amdgcn_fractf)
  return __builtin_amdgcn_fractf(x);
#else
  return x - floorf(x);
#endif
}
// sin(2*pi*x) for x in [0,1) — v_sin_f32 takes revolutions
__device__ __forceinline__ float hw_sin1(float x) {
#if __has_builtin(__builtin_amdgcn_sinf)
  return __builtin_amdgcn_sinf(x);
#else
  return __sinf(x * 6.283185307179586f);
#endif
}

// ---------------- Kernel A: per-1024-chunk f64 sums of f0 ----------------
__global__ __launch_bounds__(256) void sg_partial(const float* __restrict__ f0,
                                                  double* __restrict__ part) {
  const int c = blockIdx.x, b = blockIdx.y, t = threadIdx.x;
  const int i4 = c * 256 + t;
  float4 v = make_float4(0.f, 0.f, 0.f, 0.f);
  if (i4 < LEN / 4) v = ((const float4*)(f0 + (size_t)b * LEN))[i4];
  double s = (double)((v.x + v.y) + (v.z + v.w));
#pragma unroll
  for (int d = 32; d > 0; d >>= 1) s += __shfl_down(s, d, 64);
  __shared__ double ws[4];
  if ((t & 63) == 0) ws[t >> 6] = s;
  __syncthreads();
  if (t == 0) part[(size_t)b * NCHUNK + c] = (ws[0] + ws[1]) + (ws[2] + ws[3]);
}

// ---------------- Kernel B: main ----------------
// LDS holds only the scan results (P[1024] + amp[1024], ~8.5 KB) instead of
// the full 36 KB output tile: occupancy 4 -> 8 blocks/CU, and sines are computed
// directly in store order (element/harmonic index from unrolled div-by-9),
// removing the compute->LDS->reload round-trip. Math is bitwise-identical to
// the 36 KB-tile version (same P prefix values, same f64 phi0/hsf, same
// fract/sin sequence).
__global__ __launch_bounds__(256) void sg_main(const float* __restrict__ f0,
                                               const float* __restrict__ rand_ini,
                                               const double* __restrict__ part,
                                               float* __restrict__ out) {
  const int c = blockIdx.x, b = blockIdx.y, t = threadIdx.x;
  const int lane = t & 63, w = t >> 6;

  __shared__ __align__(16) float Pl[CHUNK + 4];  // inclusive prefix per element
  __shared__ __align__(16) float Al[CHUNK + 4];  // amp (0.1*uv) per element
  __shared__ float2 Hl[NDIM];                    // {phi0, hsf} per harmonic
  __shared__ float wsc[4];
  __shared__ double dred[4];

  // --- load this thread's 4 elements (coalesced float4) ---
  const int i4 = c * 256 + t;
  float4 v = make_float4(0.f, 0.f, 0.f, 0.f);
  if (i4 < LEN / 4) v = ((const float4*)(f0 + (size_t)b * LEN))[i4];
  const float gs = (v.x + v.y) + (v.z + v.w);

  // --- block-parallel f64 sum of preceding chunk sums ---
  const double* prow = part + (size_t)b * NCHUNK;
  double s = 0.0;
  if (t < c) s += prow[t];
  if (t + 256 < c) s += prow[t + 256];
#pragma unroll
  for (int d = 32; d > 0; d >>= 1) s += __shfl_down(s, d, 64);
  if (lane == 0) dred[w] = s;

  // --- wave-level inclusive scan of per-thread group sums ---
  float x = gs;
#pragma unroll
  for (int d = 1; d < 64; d <<= 1) {
    float y = __shfl_up(x, d, 64);
    if (lane >= d) x += y;
  }
  if (lane == 63) wsc[w] = x;
  __syncthreads();

  // --- per-harmonic base phase, computed by 9 threads only ---
  if (t < NDIM) {
    const double cb = (dred[0] + dred[1]) + (dred[2] + dred[3]);
    const double hs = (double)(t + 1) * (1.0 / 24000.0);
    double p0 = (double)rand_ini[b * NDIM + t] + hs * cb;
    p0 -= floor(p0);
    Hl[t] = make_float2((float)p0, (float)hs);
  }

  const float t0 = wsc[0], t1 = wsc[1], t2 = wsc[2];
  const float wpre = (w > 0 ? t0 : 0.f) + (w > 1 ? t1 : 0.f) + (w > 2 ? t2 : 0.f);
  const float Pex = wpre + (x - gs);    // exclusive in-chunk prefix

  // --- per-element inclusive prefix + amp into LDS (b128, 2-way = free) ---
  const float p0v = Pex + v.x;
  const float p1v = p0v + v.y;
  const float p2v = p1v + v.z;
  const float p3v = p2v + v.w;
  {
    vfloat4 pq; pq.x = p0v; pq.y = p1v; pq.z = p2v; pq.w = p3v;
    *(vfloat4*)&Pl[4 * t] = pq;
    vfloat4 aq;
    aq.x = (v.x > 0.f) ? AMP : 0.f;
    aq.y = (v.y > 0.f) ? AMP : 0.f;
    aq.z = (v.z > 0.f) ? AMP : 0.f;
    aq.w = (v.w > 0.f) ? AMP : 0.f;
    *(vfloat4*)&Al[4 * t] = aq;
  }
  __syncthreads();

  // --- compute sines directly in coalesced store order ---
  vfloat4* out4 = (vfloat4*)out;
  const int base = c * CHUNK;
  const int valid = min(CHUNK, LEN - base);
  const int nf4 = (valid * NDIM) >> 2;
  const size_t gb4 = ((size_t)b * LEN * NDIM + (size_t)base * NDIM) >> 2;

  const int f0i = 4 * t;            // first float index owned this iteration
  const int q0 = f0i / 9;           // magic-div by compiler
  const int r0 = f0i % 9;

#pragma unroll
  for (int k = 0; k < 9; ++k) {
    const int idx = k * 256 + t;    // float4 index within chunk
    const int K9 = (1024 * k) / 9;  // compile-time
    const int rk = (1024 * k) % 9;  // compile-time
    const int rsum = r0 + rk;       // [0,16]
    const int carry = (rsum >= 9) ? 1 : 0;
    const int e = q0 + K9 + carry;  // element of float 4*idx
    const int r = rsum - 9 * carry; // harmonic of float 4*idx
    const float PA = Pl[e], PB = Pl[e + 1];
    const float aA = Al[e], aB = Al[e + 1];
    float res[4];
#pragma unroll
    for (int j = 0; j < 4; ++j) {
      const int h = r + j;
      const bool crs = (h >= 9);
      const int hh = crs ? h - 9 : h;
      const float2 ph = Hl[hh];                 // LDS lookup, mostly broadcast
      const float Pe = crs ? PB : PA;
      const float am = crs ? aB : aA;
      res[j] = am * hw_sin1(hw_fract(ph.x + ph.y * Pe));
    }
    if (idx < nf4) {
      vfloat4 q; q.x = res[0]; q.y = res[1]; q.z = res[2]; q.w = res[3];
      __builtin_nontemporal_store(q, &out4[gb4 + idx]);
    }
  }

  // --- uv store (from registers, coalesced) ---
  const size_t uv4_base = ((size_t)BATCH * LEN * NDIM) / 4 + ((size_t)b * LEN) / 4;
  if (i4 < LEN / 4) {
    vfloat4 u;
    u.x = (v.x > 0.f) ? 1.f : 0.f;
    u.y = (v.y > 0.f) ? 1.f : 0.f;
    u.z = (v.z > 0.f) ? 1.f : 0.f;
    u.w = (v.w > 0.f) ? 1.f : 0.f;
    __builtin_nontemporal_store(u, &out4[uv4_base + i4]);
  }
}

extern "C" void kernel_launch(void* const* d_in, const int* in_sizes, int n_in,
                              void* d_out, int out_size, void* d_ws, size_t ws_size,
                              hipStream_t stream) {
  const float* f0 = (const float*)d_in[0];
  const float* rand_ini = (const float*)d_in[1];
  float* out = (float*)d_out;

  double* part = (double*)d_ws;   // BATCH*NCHUNK f64 partial chunk sums

  dim3 grid(NCHUNK, BATCH);
  sg_partial<<<grid, 256, 0, stream>>>(f0, part);
  sg_main<<<grid, 256, 0, stream>>>(f0, rand_ini, part, out);
}